// Round 10
// baseline (936.687 us; speedup 1.0000x reference)
//
#include <hip/hip_runtime.h>

#define N_ENEMY 4000000
#define N_GUN   1000000
#define N_EDGES 16000000
#define OUTD    8

// ---- quarters pipeline config ----
#define QE    4000000           // edges per pass (4 passes)
#define ST    8192              // sscatter tile
#define SEPT  32                // ST/256
#define NT_Q  489               // ceil(QE/ST)
#define SB    1024              // src buckets (windows of 4096 enemies = 32KB bf16)
#define SSH   12                // src_local = src & 4095, sb = src >> 12
#define RT    4096              // dscatter chunk
#define RD    16                // RT/256
#define TPB   2                 // chunks per src bucket (cap 8192 = mean+68 sigma)
#define DG    (SB*TPB)          // 2048
#define NDB   512               // dst buckets (2048 guns each)
#define DSH   11

__device__ __forceinline__ unsigned int rne_bf16(unsigned int u) {
    return (u + 0x7FFFu + ((u >> 16) & 1u)) >> 16;
}

// ---- Fold W_l@W_fc (4x8), W_r@W_fc (8), b_l@W_fc + b_fc (8) into P[48] ----
__global__ void prep_params(const float* __restrict__ W_l, const float* __restrict__ b_l,
                            const float* __restrict__ W_r, const float* __restrict__ W_fc,
                            const float* __restrict__ b_fc, float* __restrict__ P) {
    int o = threadIdx.x;
    if (o < OUTD) {
        float a0 = 0.f, a1 = 0.f, a2 = 0.f, a3 = 0.f, r = 0.f, c = 0.f;
        for (int h = 0; h < 64; ++h) {
            float w = W_fc[h * OUTD + o];
            a0 += W_l[0 * 64 + h] * w;
            a1 += W_l[1 * 64 + h] * w;
            a2 += W_l[2 * 64 + h] * w;
            a3 += W_l[3 * 64 + h] * w;
            r  += W_r[h] * w;
            c  += b_l[h] * w;
        }
        P[0 * OUTD + o] = a0;
        P[1 * OUTD + o] = a1;
        P[2 * OUTD + o] = a2;
        P[3 * OUTD + o] = a3;
        P[4 * OUTD + o] = r;
        P[5 * OUTD + o] = c + b_fc[o];
    }
}

// ---- per-tile src-bucket histogram (quarter-local) ----
__global__ void shist_q(const int* __restrict__ esrc, unsigned short* __restrict__ stileh) {
    __shared__ unsigned int lh[SB];
    int t = threadIdx.x;
    for (int i = t; i < SB; i += 256) lh[i] = 0;
    __syncthreads();
    int lt = blockIdx.x * ST;
    int n = QE - lt; if (n > ST) n = ST;
    for (int i = t; i < n; i += 256)
        atomicAdd(&lh[((unsigned)esrc[lt + i]) >> SSH], 1u);
    __syncthreads();
    unsigned short* row = stileh + (size_t)blockIdx.x * SB;
    for (int i = t; i < SB; i += 256) row[i] = (unsigned short)lh[i];
}

// ---- generic per-bucket exclusive prefix over tiles (in-place) + totals ----
template<int K>
__global__ __launch_bounds__(256)
void tile_scanT(unsigned short* __restrict__ tileh, unsigned int* __restrict__ tot,
                int nbk, int ntile) {
    __shared__ unsigned int part[256][17];
    int t = threadIdx.x;
    int b0 = blockIdx.x * 16;
    unsigned int loc[16];
#pragma unroll
    for (int j = 0; j < 16; ++j) loc[j] = 0;
    for (int k = 0; k < K; ++k) {
        int tile = t * K + k;
        if (tile < ntile) {
            const unsigned short* row = tileh + (size_t)tile * nbk + b0;
#pragma unroll
            for (int j = 0; j < 16; ++j) loc[j] += row[j];
        }
    }
#pragma unroll
    for (int j = 0; j < 16; ++j) part[t][j] = loc[j];
    __syncthreads();
    if (t < 16) {
        unsigned int acc = 0;
        for (int i = 0; i < 256; ++i) {
            unsigned int v = part[i][t];
            part[i][t] = acc;
            acc += v;
        }
        tot[b0 + t] = acc;
    }
    __syncthreads();
    unsigned int run[16];
#pragma unroll
    for (int j = 0; j < 16; ++j) run[j] = part[t][j];
    for (int k = 0; k < K; ++k) {
        int tile = t * K + k;
        if (tile < ntile) {
            unsigned short* row = tileh + (size_t)tile * nbk + b0;
#pragma unroll
            for (int j = 0; j < 16; ++j) {
                unsigned int c = row[j];
                row[j] = (unsigned short)run[j];
                run[j] += c;
            }
        }
    }
}

__global__ void scan1024(const unsigned int* __restrict__ tot, unsigned int* __restrict__ offs) {
    __shared__ unsigned int tmp[1024];
    int t = threadIdx.x;
    unsigned int v0 = tot[t];
    tmp[t] = v0;
    __syncthreads();
    for (int d = 1; d < 1024; d <<= 1) {
        unsigned int v = (t >= d) ? tmp[t - d] : 0u;
        __syncthreads();
        tmp[t] += v;
        __syncthreads();
    }
    offs[t] = tmp[t] - v0;
    if (t == 1023) offs[1024] = tmp[t];
}

__global__ void scan512(const unsigned int* __restrict__ tot, unsigned int* __restrict__ offs) {
    __shared__ unsigned int tmp[512];
    int t = threadIdx.x;
    unsigned int v0 = tot[t];
    tmp[t] = v0;
    __syncthreads();
    for (int d = 1; d < 512; d <<= 1) {
        unsigned int v = (t >= d) ? tmp[t - d] : 0u;
        __syncthreads();
        tmp[t] += v;
        __syncthreads();
    }
    offs[t] = tmp[t] - v0;
    if (t == 511) offs[512] = tmp[t];
}

// ---- tile-sort (quarter) by src bucket; rec = (src_local<<20)|dst; no atomics ----
__global__ __launch_bounds__(256)
void sscatter_q(const int* __restrict__ esrc, const int* __restrict__ edst,
                const unsigned int* __restrict__ sOffs,
                const unsigned short* __restrict__ stileh,
                unsigned int* __restrict__ rec) {
    __shared__ unsigned int cnt[SB];
    __shared__ unsigned int base_[SB];
    __shared__ unsigned short bOf[ST];
    __shared__ unsigned int sortR[ST];
    __shared__ unsigned int partial[256];
    int t = threadIdx.x;
    int tile = blockIdx.x;
    int lt = tile * ST;
    int n = QE - lt; if (n > ST) n = ST;

    for (int i = t; i < SB; i += 256) cnt[i] = 0;
    __syncthreads();

    unsigned int w[SEPT], br[SEPT];
#pragma unroll
    for (int k = 0; k < SEPT; ++k) {
        int idx = k * 256 + t;
        if (idx < n) {
            unsigned int s = (unsigned int)esrc[lt + idx];
            unsigned int d = (unsigned int)edst[lt + idx];
            unsigned int b = s >> SSH;
            unsigned int r = atomicAdd(&cnt[b], 1u);
            w[k]  = ((s & 4095u) << 20) | d;
            br[k] = (b << 13) | r;
        } else br[k] = 0xFFFFFFFFu;
    }
    __syncthreads();

    unsigned int loc[4];
    unsigned int acc = 0;
#pragma unroll
    for (int j = 0; j < 4; ++j) {
        int b = t * 4 + j;
        unsigned int c = cnt[b];
        loc[j] = acc; acc += c;
    }
    partial[t] = acc;
    __syncthreads();
    for (int d = 1; d < 256; d <<= 1) {
        unsigned int v = (t >= d) ? partial[t - d] : 0u;
        __syncthreads();
        partial[t] += v;
        __syncthreads();
    }
    unsigned int excl = (t > 0) ? partial[t - 1] : 0u;
#pragma unroll
    for (int j = 0; j < 4; ++j) base_[t * 4 + j] = excl + loc[j];
    __syncthreads();

#pragma unroll
    for (int j = 0; j < 4; ++j) {
        int b = t * 4 + j;
        unsigned int bs = base_[b], c = cnt[b];
        for (unsigned int p = bs; p < bs + c; ++p) bOf[p] = (unsigned short)b;
    }
    __syncthreads();

#pragma unroll
    for (int k = 0; k < SEPT; ++k) {
        if (br[k] != 0xFFFFFFFFu) {
            unsigned int b = br[k] >> 13, r = br[k] & 8191u;
            sortR[base_[b] + r] = w[k];
        }
    }
    __syncthreads();

    const unsigned short* trow = stileh + (size_t)tile * SB;
    for (int p = t; p < n; p += 256) {
        unsigned int b = bOf[p];
        rec[sOffs[b] + (unsigned int)trow[b] + ((unsigned int)p - base_[b])] = sortR[p];
    }
}

// ---- per-(src-bucket,chunk) dst-bucket histogram ----
__global__ void dhist_q(const unsigned int* __restrict__ rec,
                        const unsigned int* __restrict__ sOffs,
                        unsigned short* __restrict__ dtileh) {
    __shared__ unsigned int lh[NDB];
    int t = threadIdx.x;
    for (int i = t; i < NDB; i += 256) lh[i] = 0;
    __syncthreads();
    int sb = blockIdx.x / TPB, chunk = blockIdx.x % TPB;
    unsigned int segE = sOffs[sb + 1];
    unsigned int st = sOffs[sb] + (unsigned int)chunk * RT;
    int n = (st < segE) ? (int)((segE - st < RT) ? (segE - st) : RT) : 0;
    for (int i = t; i < n; i += 256)
        atomicAdd(&lh[(rec[st + i] & 0xFFFFFu) >> DSH], 1u);
    __syncthreads();
    unsigned short* row = dtileh + (size_t)blockIdx.x * NDB;
    for (int i = t; i < NDB; i += 256) row[i] = (unsigned short)lh[i];
}

// ---- fused LDS-window gather + dst-bucket tile sort -> (val u64, g u16) streams ----
__global__ __launch_bounds__(256)
void dscatter_q(const unsigned int* __restrict__ rec, const uint4* __restrict__ xe,
                const unsigned int* __restrict__ sOffs, const unsigned int* __restrict__ dOffs,
                const unsigned short* __restrict__ dtileh,
                unsigned long long* __restrict__ val, unsigned short* __restrict__ gArr) {
    __shared__ unsigned long long win[4096];   // 32KB bf16x4 window
    __shared__ unsigned int cnt[NDB];
    __shared__ unsigned int base_[NDB];
    __shared__ unsigned short bOf[RT];
    __shared__ unsigned int sortW[RT];
    __shared__ unsigned int partial[256];
    int t = threadIdx.x;
    int sb = blockIdx.x;

    // load + convert window once per src bucket
    for (int j = t; j < 4096; j += 256) {
        unsigned int idx = ((unsigned int)sb << SSH) + j;
        if (idx < N_ENEMY) {
            uint4 v = xe[idx];
            unsigned long long lo = (unsigned long long)(rne_bf16(v.x) | (rne_bf16(v.y) << 16));
            unsigned long long hi = (unsigned long long)(rne_bf16(v.z) | (rne_bf16(v.w) << 16));
            win[j] = lo | (hi << 32);
        }
    }
    unsigned int segS = sOffs[sb], segE = sOffs[sb + 1];

    for (int chunk = 0; chunk < TPB; ++chunk) {
        unsigned int st = segS + (unsigned int)chunk * RT;
        if (st >= segE) break;
        int n = (int)((segE - st < RT) ? (segE - st) : RT);

        cnt[t] = 0; cnt[t + 256] = 0;
        __syncthreads();

        unsigned int w[RD], br[RD];
#pragma unroll
        for (int k = 0; k < RD; ++k) {
            int idx = k * 256 + t;
            if (idx < n) {
                unsigned int r = rec[st + idx];
                unsigned int dst = r & 0xFFFFFu;
                unsigned int db = dst >> DSH;
                unsigned int rk = atomicAdd(&cnt[db], 1u);
                w[k]  = ((r >> 20) << DSH) | (dst & 2047u);   // (src_local<<11)|g
                br[k] = (db << 13) | rk;
            } else br[k] = 0xFFFFFFFFu;
        }
        __syncthreads();

        unsigned int c0 = cnt[2 * t], c1 = cnt[2 * t + 1];
        partial[t] = c0 + c1;
        __syncthreads();
        for (int d = 1; d < 256; d <<= 1) {
            unsigned int v = (t >= d) ? partial[t - d] : 0u;
            __syncthreads();
            partial[t] += v;
            __syncthreads();
        }
        unsigned int excl = (t > 0) ? partial[t - 1] : 0u;
        base_[2 * t] = excl;
        base_[2 * t + 1] = excl + c0;
        __syncthreads();

        {
            unsigned int bs = base_[2 * t];
            for (unsigned int p = bs; p < bs + c0; ++p) bOf[p] = (unsigned short)(2 * t);
            bs = base_[2 * t + 1];
            for (unsigned int p = bs; p < bs + c1; ++p) bOf[p] = (unsigned short)(2 * t + 1);
        }
        __syncthreads();

#pragma unroll
        for (int k = 0; k < RD; ++k) {
            if (br[k] != 0xFFFFFFFFu) {
                unsigned int b = br[k] >> 13, rk = br[k] & 8191u;
                sortW[base_[b] + rk] = w[k];
            }
        }
        __syncthreads();

        const unsigned short* drow = dtileh + (size_t)(sb * TPB + chunk) * NDB;
        for (int p = t; p < n; p += 256) {
            unsigned int b = bOf[p];
            unsigned int ww = sortW[p];
            unsigned int pos = dOffs[b] + (unsigned int)drow[b] + ((unsigned int)p - base_[b]);
            val[pos] = win[ww >> DSH];
            gArr[pos] = (unsigned short)(ww & 2047u);
        }
        __syncthreads();
    }
}

// ---- aggregate pass: coalesced streams -> LDS -> global summed/counts (no atomics) ----
__global__ __launch_bounds__(256)
void agg_q(const unsigned int* __restrict__ dOffs,
           const unsigned long long* __restrict__ val,
           const unsigned short* __restrict__ gArr,
           float* __restrict__ sum, float* __restrict__ cnts) {
    __shared__ float s0[2048], s1[2048], s2[2048], s3[2048];
    __shared__ unsigned int cc[2048];
    int t = threadIdx.x;
    for (int i = t; i < 2048; i += 256) {
        s0[i] = 0.f; s1[i] = 0.f; s2[i] = 0.f; s3[i] = 0.f; cc[i] = 0u;
    }
    __syncthreads();
    unsigned int b = blockIdx.x;
    unsigned int st = dOffs[b], en = dOffs[b + 1];
    for (unsigned int i = st + (unsigned int)t; i < en; i += 256) {
        unsigned long long v = val[i];
        unsigned int g = gArr[i];
        unsigned int lo = (unsigned int)v, hi = (unsigned int)(v >> 32);
        atomicAdd(&s0[g], __uint_as_float(lo << 16));
        atomicAdd(&s1[g], __uint_as_float(lo & 0xffff0000u));
        atomicAdd(&s2[g], __uint_as_float(hi << 16));
        atomicAdd(&s3[g], __uint_as_float(hi & 0xffff0000u));
        atomicAdd(&cc[g], 1u);
    }
    __syncthreads();
    for (int gl = t; gl < 2048; gl += 256) {
        unsigned int G = (b << DSH) + (unsigned int)gl;
        if (G >= N_GUN) continue;
        float4* sp = (float4*)(sum + (size_t)G * 4);
        float4 cur = *sp;
        cur.x += s0[gl]; cur.y += s1[gl]; cur.z += s2[gl]; cur.w += s3[gl];
        *sp = cur;
        cnts[G] += (float)cc[gl];
    }
}

// ---- epilogue ----
__global__ void gun_kernel(const float4* __restrict__ summed, const float* __restrict__ counts,
                           const float* __restrict__ xg, const float* __restrict__ P,
                           float* __restrict__ out) {
    __shared__ float sP[48];
    if (threadIdx.x < 48) sP[threadIdx.x] = P[threadIdx.x];
    __syncthreads();
    int g = blockIdx.x * blockDim.x + threadIdx.x;
    if (g >= N_GUN) return;
    float4 s = summed[g];
    float cnt = counts[g];
    float inv = 1.0f / fmaxf(cnt, 1.0f);
    float m0 = s.x * inv, m1 = s.y * inv, m2 = s.z * inv, m3 = s.w * inv;
    float xv = xg[g];
    float res[OUTD];
#pragma unroll
    for (int o = 0; o < OUTD; ++o) {
        res[o] = m0 * sP[o] + m1 * sP[8 + o] + m2 * sP[16 + o] + m3 * sP[24 + o]
               + xv * sP[32 + o] + sP[40 + o];
    }
    float4* op = (float4*)(out + (size_t)g * OUTD);
    op[0] = make_float4(res[0], res[1], res[2], res[3]);
    op[1] = make_float4(res[4], res[5], res[6], res[7]);
}

// ================= atomic fallback (tiny ws) =================================
__global__ void edge_kernel(const int4* __restrict__ esrc4, const int4* __restrict__ edst4,
                            const float4* __restrict__ xe, float* __restrict__ summed,
                            float* __restrict__ counts) {
    int t = blockIdx.x * blockDim.x + threadIdx.x;
    if (t >= N_EDGES / 4) return;
    int4 s4 = esrc4[t];
    int4 d4 = edst4[t];
    int ss[4] = { s4.x, s4.y, s4.z, s4.w };
    int dd[4] = { d4.x, d4.y, d4.z, d4.w };
#pragma unroll
    for (int k = 0; k < 4; ++k) {
        float4 m = xe[ss[k]];
        float* basep = summed + (size_t)dd[k] * 4;
        atomicAdd(basep + 0, m.x);
        atomicAdd(basep + 1, m.y);
        atomicAdd(basep + 2, m.z);
        atomicAdd(basep + 3, m.w);
        atomicAdd(counts + dd[k], 1.0f);
    }
}

extern "C" void kernel_launch(void* const* d_in, const int* in_sizes, int n_in,
                              void* d_out, int out_size, void* d_ws, size_t ws_size,
                              hipStream_t stream) {
    const float* x_enemy = (const float*)d_in[0];
    const float* x_gun   = (const float*)d_in[1];
    const int*   esrc    = (const int*)d_in[2];
    const int*   edst    = (const int*)d_in[3];
    const float* W_l     = (const float*)d_in[4];
    const float* b_l     = (const float*)d_in[5];
    const float* W_r     = (const float*)d_in[6];
    const float* W_fc    = (const float*)d_in[7];
    const float* b_fc    = (const float*)d_in[8];
    float* out = (float*)d_out;

    // ws layout (u32 units), ~79 MB
    const size_t REC_OFF    = 0;                                  // QE
    const size_t VAL_OFF    = REC_OFF + (size_t)QE;               // 2*QE (u64[QE])
    const size_t G_OFF      = VAL_OFF + (size_t)QE * 2;           // QE/2 (u16[QE])
    const size_t SUM_OFF    = G_OFF + (size_t)QE / 2;             // 4M
    const size_t CNT_OFF    = SUM_OFF + (size_t)N_GUN * 4;        // 1M
    const size_t STILEH_OFF = CNT_OFF + (size_t)N_GUN;            // u16[NT_Q*SB]
    const size_t DTILEH_OFF = STILEH_OFF + ((size_t)NT_Q * SB + 1) / 2;
    const size_t STOT_OFF   = DTILEH_OFF + ((size_t)DG * NDB + 1) / 2;
    const size_t SOFFS_OFF  = STOT_OFF + SB;                      // SB+1
    const size_t DTOT_OFF   = SOFFS_OFF + SB + 1;                 // NDB
    const size_t DOFFS_OFF  = DTOT_OFF + NDB;                     // NDB+1
    const size_t P_OFF      = DOFFS_OFF + NDB + 1;                // 48
    const size_t NEEDED_Q   = (P_OFF + 64) * sizeof(unsigned int);

    if (ws_size >= NEEDED_Q) {
        unsigned int*       ws     = (unsigned int*)d_ws;
        unsigned int*       rec    = ws + REC_OFF;
        unsigned long long* val    = (unsigned long long*)(ws + VAL_OFF);
        unsigned short*     gArr   = (unsigned short*)(ws + G_OFF);
        float*              sum    = (float*)(ws + SUM_OFF);
        float*              cnts   = (float*)(ws + CNT_OFF);
        unsigned short*     stileh = (unsigned short*)(ws + STILEH_OFF);
        unsigned short*     dtileh = (unsigned short*)(ws + DTILEH_OFF);
        unsigned int*       stot   = ws + STOT_OFF;
        unsigned int*       sOffs  = ws + SOFFS_OFF;
        unsigned int*       dtot   = ws + DTOT_OFF;
        unsigned int*       dOffs  = ws + DOFFS_OFF;
        float*              P      = (float*)(ws + P_OFF);

        hipMemsetAsync(ws + SUM_OFF, 0, (size_t)N_GUN * 5 * sizeof(float), stream);
        prep_params<<<1, 64, 0, stream>>>(W_l, b_l, W_r, W_fc, b_fc, P);

        for (int q = 0; q < 4; ++q) {
            const int* qs = esrc + (size_t)q * QE;
            const int* qd = edst + (size_t)q * QE;
            shist_q<<<NT_Q, 256, 0, stream>>>(qs, stileh);
            tile_scanT<2><<<SB / 16, 256, 0, stream>>>(stileh, stot, SB, NT_Q);
            scan1024<<<1, 1024, 0, stream>>>(stot, sOffs);
            sscatter_q<<<NT_Q, 256, 0, stream>>>(qs, qd, sOffs, stileh, rec);
            dhist_q<<<DG, 256, 0, stream>>>(rec, sOffs, dtileh);
            tile_scanT<8><<<NDB / 16, 256, 0, stream>>>(dtileh, dtot, NDB, DG);
            scan512<<<1, 512, 0, stream>>>(dtot, dOffs);
            dscatter_q<<<SB, 256, 0, stream>>>(rec, (const uint4*)x_enemy, sOffs, dOffs,
                                               dtileh, val, gArr);
            agg_q<<<NDB, 256, 0, stream>>>(dOffs, val, gArr, sum, cnts);
        }
        gun_kernel<<<(N_GUN + 255) / 256, 256, 0, stream>>>(
            (const float4*)sum, cnts, x_gun, P, out);
    } else {
        float* summed = (float*)d_ws;
        float* counts = summed + (size_t)N_GUN * 4;
        float* P      = counts + N_GUN;
        hipMemsetAsync(d_ws, 0, ((size_t)N_GUN * 5 + 48) * sizeof(float), stream);
        prep_params<<<1, 64, 0, stream>>>(W_l, b_l, W_r, W_fc, b_fc, P);
        int edge_threads = N_EDGES / 4;
        edge_kernel<<<(edge_threads + 255) / 256, 256, 0, stream>>>(
            (const int4*)esrc, (const int4*)edst, (const float4*)x_enemy, summed, counts);
        gun_kernel<<<(N_GUN + 255) / 256, 256, 0, stream>>>(
            (const float4*)summed, counts, x_gun, P, out);
    }
}